// Round 10
// baseline (3012.449 us; speedup 1.0000x reference)
//
#include <hip/hip_runtime.h>
#include <cstdint>
#include <cstddef>

#define BB 8
#define NN 4096
#define FF 64
#define SS 2048
#define KK 64
#define H1c 64
#define H2c 64
#define H3c 128
#define R2 0.04f
#define CAP 448
#define NFPS 4   // fps blocks, 2 clouds each
#define NY1 240  // y1-role blocks; grid = 4+1+240 = 245 <= 256 CUs

typedef unsigned long long ull;
typedef __attribute__((ext_vector_type(4))) float f32x4;
typedef __attribute__((ext_vector_type(8))) short bf16x8;

// Exact (numpy-order, non-fma) squared distance: (dx*dx + dy*dy) + dz*dz
__device__ __forceinline__ float d2_exact(float ax, float ay, float az,
                                          float bx, float by, float bz) {
  float dx = __fsub_rn(ax, bx);
  float dy = __fsub_rn(ay, by);
  float dz = __fsub_rn(az, bz);
  return __fadd_rn(__fadd_rn(__fmul_rn(dx, dx), __fmul_rn(dy, dy)), __fmul_rn(dz, dz));
}

// round-to-nearest-even float -> bf16 bits
__device__ __forceinline__ unsigned short f2bf(float f) {
  unsigned u = __float_as_uint(f);
  return (unsigned short)((u + 0x7fffu + ((u >> 16) & 1u)) >> 16);
}

#define WAVE_MAX_DPP(v)                                                        \
  do {                                                                         \
    v = max(v, __builtin_amdgcn_update_dpp(0, v, 0x111, 0xf, 0xf, true));      \
    v = max(v, __builtin_amdgcn_update_dpp(0, v, 0x112, 0xf, 0xf, true));      \
    v = max(v, __builtin_amdgcn_update_dpp(0, v, 0x114, 0xf, 0xf, true));      \
    v = max(v, __builtin_amdgcn_update_dpp(0, v, 0x118, 0xf, 0xf, true));      \
    v = max(v, __builtin_amdgcn_update_dpp(0, v, 0x142, 0xf, 0xf, true));      \
    v = max(v, __builtin_amdgcn_update_dpp(0, v, 0x143, 0xf, 0xf, true));      \
  } while (0)

// ---------------- Kernel 1: fused FPS (blocks 0-3, 2 clouds each) -----------
// + prep (block 4) + y1 (blocks 5..244).
// FPS: 512 threads, 8 pts/thread/cloud, points in REGISTERS only. Per step
// per cloud: d2+fmin update, value max tree, combined descending scan ->
// (lidx, winner coords) in-register, DPP wave value-max, ballot+ctz -> winner
// lane publishes (key, x,y,z) pre-barrier; ONE barrier for both clouds; all
// threads tournament keys+coords (no dependent coord gather).
__global__ __launch_bounds__(512) void fused_kernel(
    const float* __restrict__ pos, const float* __restrict__ x,
    const float* __restrict__ W1, const float* __restrict__ b1,
    const float* __restrict__ W2, const float* __restrict__ W3,
    float* __restrict__ pos_out, float* __restrict__ batch_out,
    unsigned short* __restrict__ y1b, unsigned short* __restrict__ w2p,
    unsigned short* __restrict__ w3p) {
  __shared__ float xs[64][65];          // y1 role only
  __shared__ ull skey[2][2][8];         // [buf][cloud][wave]
  __shared__ f32x4 scoord[2][2][8];
  const int tid = threadIdx.x;

  if (blockIdx.x < NFPS) {
    // ================= FPS role: clouds b0, b0+1 =================
    const int b0 = blockIdx.x * 2;
    const int lane = tid & 63, wv = tid >> 6;

    float px[2][8], py[2][8], pz[2][8], dmin[2][8];
    float cx[2], cy[2], cz[2];
#pragma unroll
    for (int c = 0; c < 2; ++c) {
      const float* pb = pos + (size_t)(b0 + c) * (NN * 3) + (size_t)tid * 24;
      float f[24];
#pragma unroll
      for (int q = 0; q < 6; ++q) {
        float4 v = *(const float4*)(pb + 4 * q);
        f[4 * q + 0] = v.x;
        f[4 * q + 1] = v.y;
        f[4 * q + 2] = v.z;
        f[4 * q + 3] = v.w;
      }
#pragma unroll
      for (int i = 0; i < 8; ++i) {
        px[c][i] = f[3 * i + 0];
        py[c][i] = f[3 * i + 1];
        pz[c][i] = f[3 * i + 2];
        dmin[c][i] = INFINITY;
      }
      cx[c] = pos[(size_t)(b0 + c) * (NN * 3) + 0];
      cy[c] = pos[(size_t)(b0 + c) * (NN * 3) + 1];
      cz[c] = pos[(size_t)(b0 + c) * (NN * 3) + 2];
    }

    for (int s = 0; s < SS; ++s) {
      if (tid == 0) {
#pragma unroll
        for (int c = 0; c < 2; ++c) {
          int o = (b0 + c) * SS + s;
          pos_out[o * 3 + 0] = cx[c];
          pos_out[o * 3 + 1] = cy[c];
          pos_out[o * 3 + 2] = cz[c];
        }
      }
      const int buf = s & 1;
#pragma unroll
      for (int c = 0; c < 2; ++c) {
        // update
#pragma unroll
        for (int i = 0; i < 8; ++i) {
          float d = d2_exact(px[c][i], py[c][i], pz[c][i], cx[c], cy[c], cz[c]);
          dmin[c][i] = fminf(dmin[c][i], d);
        }
        // local value max
        float m0 = fmaxf(fmaxf(dmin[c][0], dmin[c][1]), fmaxf(dmin[c][2], dmin[c][3]));
        float m1 = fmaxf(fmaxf(dmin[c][4], dmin[c][5]), fmaxf(dmin[c][6], dmin[c][7]));
        const float lmax = fmaxf(m0, m1);
        // combined descending scan: first-occurrence index + its coords
        int lidx = 0;
        float sx = px[c][0], sy = py[c][0], sz = pz[c][0];
#pragma unroll
        for (int i = 7; i >= 1; --i) {
          bool eq = (__float_as_int(dmin[c][i]) == __float_as_int(lmax));
          lidx = eq ? i : lidx;
          sx = eq ? px[c][i] : sx;
          sy = eq ? py[c][i] : sy;
          sz = eq ? pz[c][i] : sz;
        }
        // wave value max via DPP (bit-int max exact for non-negative floats)
        const int lv = __float_as_int(lmax);
        int v = lv;
        WAVE_MAX_DPP(v);
        const int wmax = __builtin_amdgcn_readlane(v, 63);
        const ull bal = __ballot(lv == wmax);
        const int wl = (int)__builtin_ctzll(bal);
        if (lane == wl) {
          const int gidx = tid * 8 + lidx;
          skey[buf][c][wv] = ((ull)(unsigned)wmax << 32) | (unsigned)(~gidx);
          scoord[buf][c][wv] = (f32x4){sx, sy, sz, 0.f};
        }
      }
      __syncthreads();
#pragma unroll
      for (int c = 0; c < 2; ++c) {
        ull bk = skey[buf][c][0];
        f32x4 bc = scoord[buf][c][0];
#pragma unroll
        for (int q = 1; q < 8; ++q) {
          ull kq = skey[buf][c][q];
          f32x4 cq = scoord[buf][c][q];
          if (kq > bk) { bk = kq; bc = cq; }
        }
        cx[c] = bc.x;
        cy[c] = bc.y;
        cz[c] = bc.z;
      }
    }
    for (int i = tid; i < SS; i += 512) {
      batch_out[(b0 + 0) * SS + i] = (float)(b0 + 0);
      batch_out[(b0 + 1) * SS + i] = (float)(b0 + 1);
    }
    return;
  }

  if (blockIdx.x == NFPS) {
    // ================= prep role: pack W2/W3 into MFMA B-fragment order ====
    for (int e = tid; e < 4096; e += 512) {
      int j = e & 7, l = (e >> 3) & 63, s = (e >> 9) & 1, c = e >> 10;
      w2p[e] = f2bf(W2[(s * 32 + 8 * (l >> 4) + j) * H2c + c * 16 + (l & 15)]);
    }
    for (int e = tid; e < 8192; e += 512) {
      int j = e & 7, l = (e >> 3) & 63, s = (e >> 9) & 1, c = e >> 10;
      w3p[e] = f2bf(W3[(s * 32 + 8 * (l >> 4) + j) * H3c + c * 16 + (l & 15)]);
    }
    return;
  }

  // ================= y1 role: y1 = x @ W1[0:64,:] + b1 -> bf16 =============
  const int cid = blockIdx.x - NFPS - 1;  // 0..NY1-1
  for (int t = cid; t < 512; t += NY1) {
    const int r0 = t * 64;
    const float4* src = (const float4*)(x + (size_t)r0 * FF);
#pragma unroll
    for (int q = 0; q < 2; q++) {
      int p = tid + q * 512;
      float4 v = src[p];
      int row = (p * 4) >> 6, col = (p * 4) & 63;
      xs[row][col + 0] = v.x;
      xs[row][col + 1] = v.y;
      xs[row][col + 2] = v.z;
      xs[row][col + 3] = v.w;
    }
    __syncthreads();
    const int c4 = (tid & 15) * 4, kb = (tid >> 4) * 2;
    float acc[2][4];
#pragma unroll
    for (int kq = 0; kq < 2; kq++) {
      acc[kq][0] = b1[c4 + 0];
      acc[kq][1] = b1[c4 + 1];
      acc[kq][2] = b1[c4 + 2];
      acc[kq][3] = b1[c4 + 3];
    }
    for (int f = 0; f < FF; ++f) {
      float4 w = *(const float4*)(W1 + f * H1c + c4);
#pragma unroll
      for (int kq = 0; kq < 2; kq++) {
        float a = xs[kb + kq][f];
        acc[kq][0] += a * w.x;
        acc[kq][1] += a * w.y;
        acc[kq][2] += a * w.z;
        acc[kq][3] += a * w.w;
      }
    }
#pragma unroll
    for (int kq = 0; kq < 2; kq++) {
      ushort4 o;
      o.x = f2bf(acc[kq][0]);
      o.y = f2bf(acc[kq][1]);
      o.z = f2bf(acc[kq][2]);
      o.w = f2bf(acc[kq][3]);
      *(ushort4*)(y1b + (size_t)(r0 + kb + kq) * H1c + c4) = o;
    }
    __syncthreads();
  }
}

// ---------------- Kernel 2: ball query with rank-based parallel select ------
__global__ __launch_bounds__(256) void ballq_kernel(const float* __restrict__ pos,
                                                    const float* __restrict__ pos_out,
                                                    int* __restrict__ nbr) {
  __shared__ float plds[NN * 3];
  __shared__ __align__(16) ull kc[4][CAP];
  const int tid = threadIdx.x;
  const int b = blockIdx.x >> 6;
  const int chunk = blockIdx.x & 63;
  const float4* src = (const float4*)(pos + (size_t)b * NN * 3);
  float4* dstl = (float4*)plds;
#pragma unroll
  for (int k = 0; k < 12; k++) dstl[tid + k * 256] = src[tid + k * 256];
  __syncthreads();

  const int w = tid >> 6, lane = tid & 63;
  for (int t8 = 0; t8 < 8; ++t8) {
    const int s = chunk * 32 + w * 8 + t8;
    const int g = b * SS + s;
    const float cx = pos_out[g * 3 + 0], cy = pos_out[g * 3 + 1], cz = pos_out[g * 3 + 2];
    int cnt = 0;
    for (int t = 0; t < 64; ++t) {
      int j = t * 64 + lane;
      float d2 = d2_exact(plds[j * 3 + 0], plds[j * 3 + 1], plds[j * 3 + 2], cx, cy, cz);
      bool pred = (d2 <= R2);
      unsigned long long mask = __ballot(pred);
      if (pred) {
        int p = cnt + __popcll(mask & ((1ull << lane) - 1ull));
        if (p < CAP) kc[w][p] = ((ull)__float_as_uint(d2) << 32) | (unsigned)j;
      }
      cnt += (int)__popcll(mask);
    }
    int M = cnt < CAP ? cnt : CAP;
    __syncthreads();

    if (M <= 64) {
      int v = (lane < M) ? (b * NN + (int)(unsigned)(kc[w][lane] & 0xffffffffu)) : -1;
      nbr[(size_t)g * KK + lane] = v;
    } else {
      ull mk[7];
      int rk[7];
#pragma unroll
      for (int q = 0; q < 7; q++) {
        int p = lane + q * 64;
        mk[q] = (p < M) ? kc[w][p] : ~0ull;
        rk[q] = 0;
      }
      int i = 0;
      for (; i + 2 <= M; i += 2) {
        ull ka = kc[w][i], kb2 = kc[w][i + 1];
#pragma unroll
        for (int q = 0; q < 7; q++)
          rk[q] += (int)(ka < mk[q]) + (int)(kb2 < mk[q]);
      }
      if (i < M) {
        ull ka = kc[w][i];
#pragma unroll
        for (int q = 0; q < 7; q++) rk[q] += (int)(ka < mk[q]);
      }
#pragma unroll
      for (int q = 0; q < 7; q++) {
        int p = lane + q * 64;
        if (p < M && rk[q] < KK)
          nbr[(size_t)g * KK + rk[q]] = b * NN + (int)(unsigned)(mk[q] & 0xffffffffu);
      }
    }
    __syncthreads();
  }
}

// ---------------- Kernel 3: MFMA MLP, 4 centroids per block -----------------
__global__ __launch_bounds__(256) void mlp_kernel(
    const float* __restrict__ pos, const unsigned short* __restrict__ y1b,
    const float* __restrict__ W1, const float* __restrict__ b2,
    const float* __restrict__ b3, const unsigned short* __restrict__ w2p,
    const unsigned short* __restrict__ w3p, const int* __restrict__ nbr,
    const float* __restrict__ pos_out, float* __restrict__ x_out) {
  __shared__ __align__(16) unsigned short lw2[4096];
  __shared__ __align__(16) unsigned short lw3[8192];
  __shared__ float w1r[3][64];
  __shared__ int nl[64];
  __shared__ float red[4][128];
  __shared__ __align__(16) unsigned short h2t[4][16][88];
  const int tid = threadIdx.x;
  const int lane = tid & 63, wv = tid >> 6;
  const int lrow = lane & 15, g16 = lane >> 4;

  {
    const uint4* s2 = (const uint4*)w2p;
    uint4* d2v = (uint4*)lw2;
    for (int i = tid; i < 512; i += 256) d2v[i] = s2[i];
    const uint4* s3 = (const uint4*)w3p;
    uint4* d3v = (uint4*)lw3;
    for (int i = tid; i < 1024; i += 256) d3v[i] = s3[i];
    if (tid < 192) w1r[tid / 64][tid % 64] = W1[(64 + tid / 64) * H1c + (tid % 64)];
  }
  const bf16x8* w2f = (const bf16x8*)lw2;
  const bf16x8* w3f = (const bf16x8*)lw3;

  for (int pass = 0; pass < 4; ++pass) {
    const int g = blockIdx.x * 4 + pass;
    if (tid < 64) nl[tid] = nbr[(size_t)g * KK + tid];
    const float cx = pos_out[g * 3 + 0], cy = pos_out[g * 3 + 1],
                cz = pos_out[g * 3 + 2];
    __syncthreads();

    const int r = wv * 16 + lrow;
    const int j = nl[r];

    bf16x8 a0 = (bf16x8)0, a1 = (bf16x8)0;
    if (j >= 0) {
      const float rx = pos[j * 3 + 0] - cx;
      const float ry = pos[j * 3 + 1] - cy;
      const float rz = pos[j * 3 + 2] - cz;
      const unsigned short* yr = y1b + (size_t)j * H1c;
      uint4 vlo = *(const uint4*)(yr + 8 * g16);
      uint4 vhi = *(const uint4*)(yr + 32 + 8 * g16);
      const unsigned* plo = (const unsigned*)&vlo;
      const unsigned* phi = (const unsigned*)&vhi;
#pragma unroll
      for (int q = 0; q < 4; ++q) {
        unsigned u = plo[q];
        int k0 = 8 * g16 + 2 * q;
        float e0 = __uint_as_float(u << 16) + rx * w1r[0][k0] + ry * w1r[1][k0] +
                   rz * w1r[2][k0];
        float e1 = __uint_as_float(u & 0xffff0000u) + rx * w1r[0][k0 + 1] +
                   ry * w1r[1][k0 + 1] + rz * w1r[2][k0 + 1];
        a0[2 * q] = (short)f2bf(fmaxf(e0, 0.f));
        a0[2 * q + 1] = (short)f2bf(fmaxf(e1, 0.f));
        unsigned u2 = phi[q];
        int k1 = 32 + k0;
        float f0 = __uint_as_float(u2 << 16) + rx * w1r[0][k1] + ry * w1r[1][k1] +
                   rz * w1r[2][k1];
        float f1 = __uint_as_float(u2 & 0xffff0000u) + rx * w1r[0][k1 + 1] +
                   ry * w1r[1][k1 + 1] + rz * w1r[2][k1 + 1];
        a1[2 * q] = (short)f2bf(fmaxf(f0, 0.f));
        a1[2 * q + 1] = (short)f2bf(fmaxf(f1, 0.f));
      }
    }

#pragma unroll
    for (int c = 0; c < 4; ++c) {
      float bb = b2[c * 16 + lrow];
      f32x4 acc = {bb, bb, bb, bb};
      acc = __builtin_amdgcn_mfma_f32_16x16x32_bf16(a0, w2f[(c * 2 + 0) * 64 + lane], acc, 0, 0, 0);
      acc = __builtin_amdgcn_mfma_f32_16x16x32_bf16(a1, w2f[(c * 2 + 1) * 64 + lane], acc, 0, 0, 0);
#pragma unroll
      for (int t = 0; t < 4; ++t)
        h2t[wv][4 * g16 + t][c * 16 + lrow] = f2bf(fmaxf(acc[t], 0.f));
    }

    bf16x8 a20 = *(const bf16x8*)&h2t[wv][lrow][8 * g16];
    bf16x8 a21 = *(const bf16x8*)&h2t[wv][lrow][32 + 8 * g16];

    float vmax[8];
#pragma unroll
    for (int c = 0; c < 8; ++c) {
      float bb = b3[c * 16 + lrow];
      f32x4 acc = {bb, bb, bb, bb};
      acc = __builtin_amdgcn_mfma_f32_16x16x32_bf16(a20, w3f[(c * 2 + 0) * 64 + lane], acc, 0, 0, 0);
      acc = __builtin_amdgcn_mfma_f32_16x16x32_bf16(a21, w3f[(c * 2 + 1) * 64 + lane], acc, 0, 0, 0);
      float m = -INFINITY;
#pragma unroll
      for (int t = 0; t < 4; ++t) {
        int rg = wv * 16 + 4 * g16 + t;
        float val = (nl[rg] >= 0) ? fmaxf(acc[t], 0.f) : -INFINITY;
        m = fmaxf(m, val);
      }
      m = fmaxf(m, __shfl_xor(m, 16));
      m = fmaxf(m, __shfl_xor(m, 32));
      vmax[c] = m;
    }
    if (g16 == 0) {
#pragma unroll
      for (int c = 0; c < 8; ++c) red[wv][c * 16 + lrow] = vmax[c];
    }
    __syncthreads();
    if (tid < H3c) {
      float m = fmaxf(fmaxf(red[0][tid], red[1][tid]), fmaxf(red[2][tid], red[3][tid]));
      x_out[(size_t)g * H3c + tid] = m;
    }
  }
}

extern "C" void kernel_launch(void* const* d_in, const int* in_sizes, int n_in,
                              void* d_out, int out_size, void* d_ws, size_t ws_size,
                              hipStream_t stream) {
  const float* x = (const float*)d_in[0];
  const float* pos = (const float*)d_in[1];
  // d_in[2] = batch (int32) unused: clouds are equal-size by construction
  const float* W1 = (const float*)d_in[3];
  const float* b1 = (const float*)d_in[4];
  const float* W2 = (const float*)d_in[5];
  const float* b2 = (const float*)d_in[6];
  const float* W3 = (const float*)d_in[7];
  const float* b3 = (const float*)d_in[8];

  float* out = (float*)d_out;
  float* x_out = out;                                // [B*S, 128]
  float* pos_out = out + (size_t)BB * SS * H3c;      // [B*S, 3]
  float* batch_out = pos_out + (size_t)BB * SS * 3;  // [B*S]

  const size_t y1_bytes = (size_t)BB * NN * H1c * sizeof(unsigned short);  // 4 MB
  const size_t nbr_bytes = (size_t)BB * SS * KK * sizeof(int);             // 4 MB
  const size_t w2p_bytes = 4096 * sizeof(unsigned short);
  const size_t w3p_bytes = 8192 * sizeof(unsigned short);
  if (ws_size < y1_bytes + nbr_bytes + w2p_bytes + w3p_bytes) return;
  unsigned short* y1b = (unsigned short*)d_ws;
  int* nbr = (int*)((char*)d_ws + y1_bytes);
  unsigned short* w2p = (unsigned short*)((char*)d_ws + y1_bytes + nbr_bytes);
  unsigned short* w3p = w2p + 4096;

  fused_kernel<<<NFPS + 1 + NY1, 512, 0, stream>>>(pos, x, W1, b1, W2, W3,
                                                   pos_out, batch_out, y1b, w2p, w3p);
  ballq_kernel<<<BB * 64, 256, 0, stream>>>(pos, pos_out, nbr);
  mlp_kernel<<<BB * SS / 4, 256, 0, stream>>>(pos, y1b, W1, b2, b3, w2p, w3p,
                                              nbr, pos_out, x_out);
}

// Round 11
// 1876.598 us; speedup vs baseline: 1.6053x; 1.6053x over previous
//
#include <hip/hip_runtime.h>
#include <cstdint>
#include <cstddef>

#define BB 8
#define NN 4096
#define FF 64
#define SS 2048
#define KK 64
#define H1c 64
#define H2c 64
#define H3c 128
#define R2 0.04f
#define CAP 448
#define NY1 240  // y1-role blocks; grid = 8+1+240 = 249 <= 256 CUs

typedef unsigned long long ull;
typedef __attribute__((ext_vector_type(4))) float f32x4;
typedef __attribute__((ext_vector_type(8))) short bf16x8;

// Exact (numpy-order, non-fma) squared distance: (dx*dx + dy*dy) + dz*dz
__device__ __forceinline__ float d2_exact(float ax, float ay, float az,
                                          float bx, float by, float bz) {
  float dx = __fsub_rn(ax, bx);
  float dy = __fsub_rn(ay, by);
  float dz = __fsub_rn(az, bz);
  return __fadd_rn(__fadd_rn(__fmul_rn(dx, dx), __fmul_rn(dy, dy)), __fmul_rn(dz, dz));
}

// round-to-nearest-even float -> bf16 bits
__device__ __forceinline__ unsigned short f2bf(float f) {
  unsigned u = __float_as_uint(f);
  return (unsigned short)((u + 0x7fffu + ((u >> 16) & 1u)) >> 16);
}

#define WAVE_MAX_DPP(v)                                                        \
  do {                                                                         \
    v = max(v, __builtin_amdgcn_update_dpp(0, v, 0x111, 0xf, 0xf, true));      \
    v = max(v, __builtin_amdgcn_update_dpp(0, v, 0x112, 0xf, 0xf, true));      \
    v = max(v, __builtin_amdgcn_update_dpp(0, v, 0x114, 0xf, 0xf, true));      \
    v = max(v, __builtin_amdgcn_update_dpp(0, v, 0x118, 0xf, 0xf, true));      \
    v = max(v, __builtin_amdgcn_update_dpp(0, v, 0x142, 0xf, 0xf, true));      \
    v = max(v, __builtin_amdgcn_update_dpp(0, v, 0x143, 0xf, 0xf, true));      \
  } while (0)

// ---------------- Kernel 1: fused FPS (blocks 0-7) + prep (8) + y1 (9..248) -
// FPS: 512 threads, 8 pts/thread in REGISTERS. Per step: d2+fmin update,
// value max tree, DPP wave value-max, ballot+ctz -> winner lane does an
// in-register descending scan (first-occurrence) and publishes (key,x,y,z)
// PRE-barrier; one barrier; all threads read 8 keys + 8 coord slots in
// parallel (broadcast) and tree-tournament keys+coords -> next centroid.
// No dependent LDS gather remains after the barrier.
__global__ __launch_bounds__(512) void fused_kernel(
    const float* __restrict__ pos, const float* __restrict__ x,
    const float* __restrict__ W1, const float* __restrict__ b1,
    const float* __restrict__ W2, const float* __restrict__ W3,
    float* __restrict__ pos_out, float* __restrict__ batch_out,
    unsigned short* __restrict__ y1b, unsigned short* __restrict__ w2p,
    unsigned short* __restrict__ w3p) {
  __shared__ float xs[64][65];                     // y1 role only
  __shared__ __align__(16) ull skey[2][8];         // [buf][wave]
  __shared__ __align__(16) f32x4 scoord[2][8];
  const int tid = threadIdx.x;

  if (blockIdx.x < BB) {
    // ================= FPS role =================
    const int b = blockIdx.x;
    const int lane = tid & 63, wv = tid >> 6;

    float px[8], py[8], pz[8], dmin[8];
    {
      const float* pb = pos + (size_t)b * (NN * 3) + (size_t)tid * 24;
      float f[24];
#pragma unroll
      for (int q = 0; q < 6; ++q) {
        float4 v = *(const float4*)(pb + 4 * q);
        f[4 * q + 0] = v.x;
        f[4 * q + 1] = v.y;
        f[4 * q + 2] = v.z;
        f[4 * q + 3] = v.w;
      }
#pragma unroll
      for (int i = 0; i < 8; ++i) {
        px[i] = f[3 * i + 0];
        py[i] = f[3 * i + 1];
        pz[i] = f[3 * i + 2];
        dmin[i] = INFINITY;
      }
    }
    float cx = pos[(size_t)b * (NN * 3) + 0];
    float cy = pos[(size_t)b * (NN * 3) + 1];
    float cz = pos[(size_t)b * (NN * 3) + 2];

    for (int s = 0; s < SS; ++s) {
      if (tid == 0) {
        int o = b * SS + s;
        pos_out[o * 3 + 0] = cx;
        pos_out[o * 3 + 1] = cy;
        pos_out[o * 3 + 2] = cz;
      }
      // update dmin (exact)
#pragma unroll
      for (int i = 0; i < 8; ++i) {
        float d = d2_exact(px[i], py[i], pz[i], cx, cy, cz);
        dmin[i] = fminf(dmin[i], d);
      }
      // local value max
      float m0 = fmaxf(fmaxf(dmin[0], dmin[1]), fmaxf(dmin[2], dmin[3]));
      float m1 = fmaxf(fmaxf(dmin[4], dmin[5]), fmaxf(dmin[6], dmin[7]));
      const float lmax = fmaxf(m0, m1);
      // wave value max via DPP (bit-int max exact for non-negative floats)
      const int lv = __float_as_int(lmax);
      int v = lv;
      WAVE_MAX_DPP(v);
      const int wmax = __builtin_amdgcn_readlane(v, 63);
      const ull bal = __ballot(lv == wmax);
      const int wl = (int)__builtin_ctzll(bal);
      const int buf = s & 1;
      if (lane == wl) {
        // descending first-occurrence scan: index + coords, all in registers
        int lidx = 0;
        float sx = px[0], sy = py[0], sz = pz[0];
#pragma unroll
        for (int i = 7; i >= 1; --i) {
          bool eq = (__float_as_int(dmin[i]) == wmax);
          lidx = eq ? i : lidx;
          sx = eq ? px[i] : sx;
          sy = eq ? py[i] : sy;
          sz = eq ? pz[i] : sz;
        }
        const int gidx = tid * 8 + lidx;
        skey[buf][wv] = ((ull)(unsigned)wmax << 32) | (unsigned)(~gidx);
        scoord[buf][wv] = (f32x4){sx, sy, sz, 0.f};
      }
      __syncthreads();

      // parallel broadcast reads of all 8 (key, coord) slots, tree tournament
      ull k0 = skey[buf][0], k1 = skey[buf][1], k2 = skey[buf][2],
          k3 = skey[buf][3], k4 = skey[buf][4], k5 = skey[buf][5],
          k6 = skey[buf][6], k7 = skey[buf][7];
      f32x4 q0 = scoord[buf][0], q1 = scoord[buf][1], q2 = scoord[buf][2],
            q3 = scoord[buf][3], q4 = scoord[buf][4], q5 = scoord[buf][5],
            q6 = scoord[buf][6], q7 = scoord[buf][7];
      // level 1
      ull a0 = k0, a1 = k2, a2 = k4, a3 = k6;
      f32x4 c0v = q0, c1v = q2, c2v = q4, c3v = q6;
      if (k1 > a0) { a0 = k1; c0v = q1; }
      if (k3 > a1) { a1 = k3; c1v = q3; }
      if (k5 > a2) { a2 = k5; c2v = q5; }
      if (k7 > a3) { a3 = k7; c3v = q7; }
      // level 2
      if (a1 > a0) { a0 = a1; c0v = c1v; }
      if (a3 > a2) { a2 = a3; c2v = c3v; }
      // level 3
      if (a2 > a0) { c0v = c2v; }
      cx = c0v.x;
      cy = c0v.y;
      cz = c0v.z;
    }
    for (int i = tid; i < SS; i += 512) batch_out[b * SS + i] = (float)b;
    return;
  }

  if (blockIdx.x == BB) {
    // ================= prep role: pack W2/W3 into MFMA B-fragment order ====
    for (int e = tid; e < 4096; e += 512) {
      int j = e & 7, l = (e >> 3) & 63, s = (e >> 9) & 1, c = e >> 10;
      w2p[e] = f2bf(W2[(s * 32 + 8 * (l >> 4) + j) * H2c + c * 16 + (l & 15)]);
    }
    for (int e = tid; e < 8192; e += 512) {
      int j = e & 7, l = (e >> 3) & 63, s = (e >> 9) & 1, c = e >> 10;
      w3p[e] = f2bf(W3[(s * 32 + 8 * (l >> 4) + j) * H3c + c * 16 + (l & 15)]);
    }
    return;
  }

  // ================= y1 role: y1 = x @ W1[0:64,:] + b1 -> bf16 =============
  const int cid = blockIdx.x - BB - 1;  // 0..NY1-1
  for (int t = cid; t < 512; t += NY1) {
    const int r0 = t * 64;
    const float4* src = (const float4*)(x + (size_t)r0 * FF);
#pragma unroll
    for (int q = 0; q < 2; q++) {
      int p = tid + q * 512;
      float4 v = src[p];
      int row = (p * 4) >> 6, col = (p * 4) & 63;
      xs[row][col + 0] = v.x;
      xs[row][col + 1] = v.y;
      xs[row][col + 2] = v.z;
      xs[row][col + 3] = v.w;
    }
    __syncthreads();
    const int c4 = (tid & 15) * 4, kb = (tid >> 4) * 2;
    float acc[2][4];
#pragma unroll
    for (int kq = 0; kq < 2; kq++) {
      acc[kq][0] = b1[c4 + 0];
      acc[kq][1] = b1[c4 + 1];
      acc[kq][2] = b1[c4 + 2];
      acc[kq][3] = b1[c4 + 3];
    }
    for (int f = 0; f < FF; ++f) {
      float4 w = *(const float4*)(W1 + f * H1c + c4);
#pragma unroll
      for (int kq = 0; kq < 2; kq++) {
        float a = xs[kb + kq][f];
        acc[kq][0] += a * w.x;
        acc[kq][1] += a * w.y;
        acc[kq][2] += a * w.z;
        acc[kq][3] += a * w.w;
      }
    }
#pragma unroll
    for (int kq = 0; kq < 2; kq++) {
      ushort4 o;
      o.x = f2bf(acc[kq][0]);
      o.y = f2bf(acc[kq][1]);
      o.z = f2bf(acc[kq][2]);
      o.w = f2bf(acc[kq][3]);
      *(ushort4*)(y1b + (size_t)(r0 + kb + kq) * H1c + c4) = o;
    }
    __syncthreads();
  }
}

// ---------------- Kernel 2: ball query with rank-based parallel select ------
__global__ __launch_bounds__(256) void ballq_kernel(const float* __restrict__ pos,
                                                    const float* __restrict__ pos_out,
                                                    int* __restrict__ nbr) {
  __shared__ float plds[NN * 3];
  __shared__ __align__(16) ull kc[4][CAP];
  const int tid = threadIdx.x;
  const int b = blockIdx.x >> 6;
  const int chunk = blockIdx.x & 63;
  const float4* src = (const float4*)(pos + (size_t)b * NN * 3);
  float4* dstl = (float4*)plds;
#pragma unroll
  for (int k = 0; k < 12; k++) dstl[tid + k * 256] = src[tid + k * 256];
  __syncthreads();

  const int w = tid >> 6, lane = tid & 63;
  for (int t8 = 0; t8 < 8; ++t8) {
    const int s = chunk * 32 + w * 8 + t8;
    const int g = b * SS + s;
    const float cx = pos_out[g * 3 + 0], cy = pos_out[g * 3 + 1], cz = pos_out[g * 3 + 2];
    int cnt = 0;
    for (int t = 0; t < 64; ++t) {
      int j = t * 64 + lane;
      float d2 = d2_exact(plds[j * 3 + 0], plds[j * 3 + 1], plds[j * 3 + 2], cx, cy, cz);
      bool pred = (d2 <= R2);
      unsigned long long mask = __ballot(pred);
      if (pred) {
        int p = cnt + __popcll(mask & ((1ull << lane) - 1ull));
        if (p < CAP) kc[w][p] = ((ull)__float_as_uint(d2) << 32) | (unsigned)j;
      }
      cnt += (int)__popcll(mask);
    }
    int M = cnt < CAP ? cnt : CAP;
    __syncthreads();

    if (M <= 64) {
      int v = (lane < M) ? (b * NN + (int)(unsigned)(kc[w][lane] & 0xffffffffu)) : -1;
      nbr[(size_t)g * KK + lane] = v;
    } else {
      ull mk[7];
      int rk[7];
#pragma unroll
      for (int q = 0; q < 7; q++) {
        int p = lane + q * 64;
        mk[q] = (p < M) ? kc[w][p] : ~0ull;
        rk[q] = 0;
      }
      int i = 0;
      for (; i + 2 <= M; i += 2) {
        ull ka = kc[w][i], kb2 = kc[w][i + 1];
#pragma unroll
        for (int q = 0; q < 7; q++)
          rk[q] += (int)(ka < mk[q]) + (int)(kb2 < mk[q]);
      }
      if (i < M) {
        ull ka = kc[w][i];
#pragma unroll
        for (int q = 0; q < 7; q++) rk[q] += (int)(ka < mk[q]);
      }
#pragma unroll
      for (int q = 0; q < 7; q++) {
        int p = lane + q * 64;
        if (p < M && rk[q] < KK)
          nbr[(size_t)g * KK + rk[q]] = b * NN + (int)(unsigned)(mk[q] & 0xffffffffu);
      }
    }
    __syncthreads();
  }
}

// ---------------- Kernel 3: MFMA MLP, 4 centroids per block -----------------
__global__ __launch_bounds__(256) void mlp_kernel(
    const float* __restrict__ pos, const unsigned short* __restrict__ y1b,
    const float* __restrict__ W1, const float* __restrict__ b2,
    const float* __restrict__ b3, const unsigned short* __restrict__ w2p,
    const unsigned short* __restrict__ w3p, const int* __restrict__ nbr,
    const float* __restrict__ pos_out, float* __restrict__ x_out) {
  __shared__ __align__(16) unsigned short lw2[4096];
  __shared__ __align__(16) unsigned short lw3[8192];
  __shared__ float w1r[3][64];
  __shared__ int nl[64];
  __shared__ float red[4][128];
  __shared__ __align__(16) unsigned short h2t[4][16][88];
  const int tid = threadIdx.x;
  const int lane = tid & 63, wv = tid >> 6;
  const int lrow = lane & 15, g16 = lane >> 4;

  {
    const uint4* s2 = (const uint4*)w2p;
    uint4* d2v = (uint4*)lw2;
    for (int i = tid; i < 512; i += 256) d2v[i] = s2[i];
    const uint4* s3 = (const uint4*)w3p;
    uint4* d3v = (uint4*)lw3;
    for (int i = tid; i < 1024; i += 256) d3v[i] = s3[i];
    if (tid < 192) w1r[tid / 64][tid % 64] = W1[(64 + tid / 64) * H1c + (tid % 64)];
  }
  const bf16x8* w2f = (const bf16x8*)lw2;
  const bf16x8* w3f = (const bf16x8*)lw3;

  for (int pass = 0; pass < 4; ++pass) {
    const int g = blockIdx.x * 4 + pass;
    if (tid < 64) nl[tid] = nbr[(size_t)g * KK + tid];
    const float cx = pos_out[g * 3 + 0], cy = pos_out[g * 3 + 1],
                cz = pos_out[g * 3 + 2];
    __syncthreads();

    const int r = wv * 16 + lrow;
    const int j = nl[r];

    bf16x8 a0 = (bf16x8)0, a1 = (bf16x8)0;
    if (j >= 0) {
      const float rx = pos[j * 3 + 0] - cx;
      const float ry = pos[j * 3 + 1] - cy;
      const float rz = pos[j * 3 + 2] - cz;
      const unsigned short* yr = y1b + (size_t)j * H1c;
      uint4 vlo = *(const uint4*)(yr + 8 * g16);
      uint4 vhi = *(const uint4*)(yr + 32 + 8 * g16);
      const unsigned* plo = (const unsigned*)&vlo;
      const unsigned* phi = (const unsigned*)&vhi;
#pragma unroll
      for (int q = 0; q < 4; ++q) {
        unsigned u = plo[q];
        int k0 = 8 * g16 + 2 * q;
        float e0 = __uint_as_float(u << 16) + rx * w1r[0][k0] + ry * w1r[1][k0] +
                   rz * w1r[2][k0];
        float e1 = __uint_as_float(u & 0xffff0000u) + rx * w1r[0][k0 + 1] +
                   ry * w1r[1][k0 + 1] + rz * w1r[2][k0 + 1];
        a0[2 * q] = (short)f2bf(fmaxf(e0, 0.f));
        a0[2 * q + 1] = (short)f2bf(fmaxf(e1, 0.f));
        unsigned u2 = phi[q];
        int k1 = 32 + k0;
        float f0 = __uint_as_float(u2 << 16) + rx * w1r[0][k1] + ry * w1r[1][k1] +
                   rz * w1r[2][k1];
        float f1 = __uint_as_float(u2 & 0xffff0000u) + rx * w1r[0][k1 + 1] +
                   ry * w1r[1][k1 + 1] + rz * w1r[2][k1 + 1];
        a1[2 * q] = (short)f2bf(fmaxf(f0, 0.f));
        a1[2 * q + 1] = (short)f2bf(fmaxf(f1, 0.f));
      }
    }

#pragma unroll
    for (int c = 0; c < 4; ++c) {
      float bb = b2[c * 16 + lrow];
      f32x4 acc = {bb, bb, bb, bb};
      acc = __builtin_amdgcn_mfma_f32_16x16x32_bf16(a0, w2f[(c * 2 + 0) * 64 + lane], acc, 0, 0, 0);
      acc = __builtin_amdgcn_mfma_f32_16x16x32_bf16(a1, w2f[(c * 2 + 1) * 64 + lane], acc, 0, 0, 0);
#pragma unroll
      for (int t = 0; t < 4; ++t)
        h2t[wv][4 * g16 + t][c * 16 + lrow] = f2bf(fmaxf(acc[t], 0.f));
    }

    bf16x8 a20 = *(const bf16x8*)&h2t[wv][lrow][8 * g16];
    bf16x8 a21 = *(const bf16x8*)&h2t[wv][lrow][32 + 8 * g16];

    float vmax[8];
#pragma unroll
    for (int c = 0; c < 8; ++c) {
      float bb = b3[c * 16 + lrow];
      f32x4 acc = {bb, bb, bb, bb};
      acc = __builtin_amdgcn_mfma_f32_16x16x32_bf16(a20, w3f[(c * 2 + 0) * 64 + lane], acc, 0, 0, 0);
      acc = __builtin_amdgcn_mfma_f32_16x16x32_bf16(a21, w3f[(c * 2 + 1) * 64 + lane], acc, 0, 0, 0);
      float m = -INFINITY;
#pragma unroll
      for (int t = 0; t < 4; ++t) {
        int rg = wv * 16 + 4 * g16 + t;
        float val = (nl[rg] >= 0) ? fmaxf(acc[t], 0.f) : -INFINITY;
        m = fmaxf(m, val);
      }
      m = fmaxf(m, __shfl_xor(m, 16));
      m = fmaxf(m, __shfl_xor(m, 32));
      vmax[c] = m;
    }
    if (g16 == 0) {
#pragma unroll
      for (int c = 0; c < 8; ++c) red[wv][c * 16 + lrow] = vmax[c];
    }
    __syncthreads();
    if (tid < H3c) {
      float m = fmaxf(fmaxf(red[0][tid], red[1][tid]), fmaxf(red[2][tid], red[3][tid]));
      x_out[(size_t)g * H3c + tid] = m;
    }
  }
}

extern "C" void kernel_launch(void* const* d_in, const int* in_sizes, int n_in,
                              void* d_out, int out_size, void* d_ws, size_t ws_size,
                              hipStream_t stream) {
  const float* x = (const float*)d_in[0];
  const float* pos = (const float*)d_in[1];
  // d_in[2] = batch (int32) unused: clouds are equal-size by construction
  const float* W1 = (const float*)d_in[3];
  const float* b1 = (const float*)d_in[4];
  const float* W2 = (const float*)d_in[5];
  const float* b2 = (const float*)d_in[6];
  const float* W3 = (const float*)d_in[7];
  const float* b3 = (const float*)d_in[8];

  float* out = (float*)d_out;
  float* x_out = out;                                // [B*S, 128]
  float* pos_out = out + (size_t)BB * SS * H3c;      // [B*S, 3]
  float* batch_out = pos_out + (size_t)BB * SS * 3;  // [B*S]

  const size_t y1_bytes = (size_t)BB * NN * H1c * sizeof(unsigned short);  // 4 MB
  const size_t nbr_bytes = (size_t)BB * SS * KK * sizeof(int);             // 4 MB
  const size_t w2p_bytes = 4096 * sizeof(unsigned short);
  const size_t w3p_bytes = 8192 * sizeof(unsigned short);
  if (ws_size < y1_bytes + nbr_bytes + w2p_bytes + w3p_bytes) return;
  unsigned short* y1b = (unsigned short*)d_ws;
  int* nbr = (int*)((char*)d_ws + y1_bytes);
  unsigned short* w2p = (unsigned short*)((char*)d_ws + y1_bytes + nbr_bytes);
  unsigned short* w3p = w2p + 4096;

  fused_kernel<<<BB + 1 + NY1, 512, 0, stream>>>(pos, x, W1, b1, W2, W3,
                                                 pos_out, batch_out, y1b, w2p, w3p);
  ballq_kernel<<<BB * 64, 256, 0, stream>>>(pos, pos_out, nbr);
  mlp_kernel<<<BB * SS / 4, 256, 0, stream>>>(pos, y1b, W1, b2, b3, w2p, w3p,
                                              nbr, pos_out, x_out);
}

// Round 12
// 1352.163 us; speedup vs baseline: 2.2279x; 1.3878x over previous
//
#include <hip/hip_runtime.h>
#include <cstdint>
#include <cstddef>

#define BB 8
#define NN 4096
#define FF 64
#define SS 2048
#define KK 64
#define H1c 64
#define H2c 64
#define H3c 128
#define R2 0.04f
#define CAP 448
#define NY1 240  // y1-role blocks; grid = 8+1+240 = 249 <= 256 CUs

typedef unsigned long long ull;
typedef __attribute__((ext_vector_type(4))) float f32x4;
typedef __attribute__((ext_vector_type(8))) short bf16x8;

// Exact (numpy-order, non-fma) squared distance: (dx*dx + dy*dy) + dz*dz
__device__ __forceinline__ float d2_exact(float ax, float ay, float az,
                                          float bx, float by, float bz) {
  float dx = __fsub_rn(ax, bx);
  float dy = __fsub_rn(ay, by);
  float dz = __fsub_rn(az, bz);
  return __fadd_rn(__fadd_rn(__fmul_rn(dx, dx), __fmul_rn(dy, dy)), __fmul_rn(dz, dz));
}

// round-to-nearest-even float -> bf16 bits
__device__ __forceinline__ unsigned short f2bf(float f) {
  unsigned u = __float_as_uint(f);
  return (unsigned short)((u + 0x7fffu + ((u >> 16) & 1u)) >> 16);
}

#define WAVE_MAX_DPP(v)                                                        \
  do {                                                                         \
    v = max(v, __builtin_amdgcn_update_dpp(0, v, 0x111, 0xf, 0xf, true));      \
    v = max(v, __builtin_amdgcn_update_dpp(0, v, 0x112, 0xf, 0xf, true));      \
    v = max(v, __builtin_amdgcn_update_dpp(0, v, 0x114, 0xf, 0xf, true));      \
    v = max(v, __builtin_amdgcn_update_dpp(0, v, 0x118, 0xf, 0xf, true));      \
    v = max(v, __builtin_amdgcn_update_dpp(0, v, 0x142, 0xf, 0xf, true));      \
    v = max(v, __builtin_amdgcn_update_dpp(0, v, 0x143, 0xf, 0xf, true));      \
  } while (0)

// ---------------- Kernel 1: fused FPS (blocks 0-7) + prep (8) + y1 (9..248) -
// FPS role is the R9-proven structure (1140 us) — byte-identical.
// prep role additionally writes pos as 3 planar arrays for the bqmlp kernel.
__global__ __launch_bounds__(512) void fused_kernel(
    const float* __restrict__ pos, const float* __restrict__ x,
    const float* __restrict__ W1, const float* __restrict__ b1,
    const float* __restrict__ W2, const float* __restrict__ W3,
    float* __restrict__ pos_out, float* __restrict__ batch_out,
    unsigned short* __restrict__ y1b, unsigned short* __restrict__ w2p,
    unsigned short* __restrict__ w3p, float* __restrict__ xpln,
    float* __restrict__ ypln, float* __restrict__ zpln) {
  __shared__ __align__(16) char smem[49152];
  __shared__ ull skey[2][8];
  const int tid = threadIdx.x;

  if (blockIdx.x < BB) {
    // ================= FPS role (R9 structure, verbatim) =================
    float* plds = (float*)smem;
    const int b = blockIdx.x;
    const float4* src = (const float4*)(pos + (size_t)b * NN * 3);
    float4* dstl = (float4*)plds;
#pragma unroll
    for (int k = 0; k < 6; ++k) dstl[tid + k * 512] = src[tid + k * 512];
    __syncthreads();

    float px[8], py[8], pz[8], dmin[8];
#pragma unroll
    for (int i = 0; i < 8; ++i) {
      int p = tid * 8 + i;
      px[i] = plds[p * 3 + 0];
      py[i] = plds[p * 3 + 1];
      pz[i] = plds[p * 3 + 2];
      dmin[i] = INFINITY;
    }
    const int lane = tid & 63, wv = tid >> 6;
    float cx = plds[0], cy = plds[1], cz = plds[2];

    for (int s = 0; s < SS; ++s) {
      if (tid == 0) {
        int o = b * SS + s;
        pos_out[o * 3 + 0] = cx;
        pos_out[o * 3 + 1] = cy;
        pos_out[o * 3 + 2] = cz;
      }
#pragma unroll
      for (int i = 0; i < 8; ++i) {
        float d = d2_exact(px[i], py[i], pz[i], cx, cy, cz);
        dmin[i] = fminf(dmin[i], d);
      }
      float m0 = fmaxf(fmaxf(dmin[0], dmin[1]), fmaxf(dmin[2], dmin[3]));
      float m1 = fmaxf(fmaxf(dmin[4], dmin[5]), fmaxf(dmin[6], dmin[7]));
      const float lmax = fmaxf(m0, m1);
      int lidx = 0;
#pragma unroll
      for (int i = 7; i >= 0; --i)
        if (__float_as_int(dmin[i]) == __float_as_int(lmax)) lidx = i;

      const int lv = __float_as_int(lmax);
      int v = lv;
      WAVE_MAX_DPP(v);
      const int wmax = __builtin_amdgcn_readlane(v, 63);
      const ull bal = __ballot(lv == wmax);
      const int wl = (int)__builtin_ctzll(bal);
      const int wli = __builtin_amdgcn_readlane(lidx, wl);
      const int widx = ((wv << 6) + wl) * 8 + wli;
      const int buf = s & 1;
      if (lane == 0)
        skey[buf][wv] = ((ull)(unsigned)wmax << 32) | (unsigned)(~widx);
      __syncthreads();

      ull ka = skey[buf][0];
#pragma unroll
      for (int q = 1; q < 8; ++q) {
        ull kq = skey[buf][q];
        if (kq > ka) ka = kq;
      }
      const int cur = (int)(~(unsigned)(ka & 0xffffffffu));
      cx = plds[cur * 3 + 0];
      cy = plds[cur * 3 + 1];
      cz = plds[cur * 3 + 2];
    }
    for (int i = tid; i < SS; i += 512) batch_out[b * SS + i] = (float)b;
    return;
  }

  if (blockIdx.x == BB) {
    // ================= prep role =================
    for (int e = tid; e < 4096; e += 512) {
      int j = e & 7, l = (e >> 3) & 63, s = (e >> 9) & 1, c = e >> 10;
      w2p[e] = f2bf(W2[(s * 32 + 8 * (l >> 4) + j) * H2c + c * 16 + (l & 15)]);
    }
    for (int e = tid; e < 8192; e += 512) {
      int j = e & 7, l = (e >> 3) & 63, s = (e >> 9) & 1, c = e >> 10;
      w3p[e] = f2bf(W3[(s * 32 + 8 * (l >> 4) + j) * H3c + c * 16 + (l & 15)]);
    }
    // planar position copies for bqmlp's coalesced scans
    for (int i = tid; i < BB * NN; i += 512) {
      xpln[i] = pos[3 * i + 0];
      ypln[i] = pos[3 * i + 1];
      zpln[i] = pos[3 * i + 2];
    }
    return;
  }

  // ================= y1 role: y1 = x @ W1[0:64,:] + b1 -> bf16 =============
  float(*xs)[65] = (float(*)[65])smem;
  const int cid = blockIdx.x - BB - 1;  // 0..NY1-1
  for (int t = cid; t < 512; t += NY1) {
    const int r0 = t * 64;
    const float4* src = (const float4*)(x + (size_t)r0 * FF);
#pragma unroll
    for (int q = 0; q < 2; q++) {
      int p = tid + q * 512;
      float4 v = src[p];
      int row = (p * 4) >> 6, col = (p * 4) & 63;
      xs[row][col + 0] = v.x;
      xs[row][col + 1] = v.y;
      xs[row][col + 2] = v.z;
      xs[row][col + 3] = v.w;
    }
    __syncthreads();
    const int c4 = (tid & 15) * 4, kb = (tid >> 4) * 2;
    float acc[2][4];
#pragma unroll
    for (int kq = 0; kq < 2; kq++) {
      acc[kq][0] = b1[c4 + 0];
      acc[kq][1] = b1[c4 + 1];
      acc[kq][2] = b1[c4 + 2];
      acc[kq][3] = b1[c4 + 3];
    }
    for (int f = 0; f < FF; ++f) {
      float4 w = *(const float4*)(W1 + f * H1c + c4);
#pragma unroll
      for (int kq = 0; kq < 2; kq++) {
        float a = xs[kb + kq][f];
        acc[kq][0] += a * w.x;
        acc[kq][1] += a * w.y;
        acc[kq][2] += a * w.z;
        acc[kq][3] += a * w.w;
      }
    }
#pragma unroll
    for (int kq = 0; kq < 2; kq++) {
      ushort4 o;
      o.x = f2bf(acc[kq][0]);
      o.y = f2bf(acc[kq][1]);
      o.z = f2bf(acc[kq][2]);
      o.w = f2bf(acc[kq][3]);
      *(ushort4*)(y1b + (size_t)(r0 + kb + kq) * H1c + c4) = o;
    }
    __syncthreads();
  }
}

// ---------------- Kernel 2: fused ball-query + MFMA MLP ---------------------
// 4096 blocks x 256 threads; block handles centroids g0..g0+3 (same cloud).
// Phase 1: wave wv ball-queries centroid g0+wv, scanning all 4096 points via
// coalesced float4 plane loads (L2-resident), rank-select (R8 semantics),
// neighbor ids -> LDS. Phase 2: 4 MLP passes (weights staged once).
__global__ __launch_bounds__(256) void bqmlp_kernel(
    const float* __restrict__ pos, const float* __restrict__ xpln,
    const float* __restrict__ ypln, const float* __restrict__ zpln,
    const unsigned short* __restrict__ y1b, const float* __restrict__ W1,
    const float* __restrict__ b2, const float* __restrict__ b3,
    const unsigned short* __restrict__ w2p, const unsigned short* __restrict__ w3p,
    const float* __restrict__ pos_out, float* __restrict__ x_out) {
  __shared__ __align__(16) unsigned short lw2[4096];
  __shared__ __align__(16) unsigned short lw3[8192];
  __shared__ float w1r[3][64];
  __shared__ __align__(16) ull kc[4][CAP];
  __shared__ int nbl[4][64];
  __shared__ float red[4][128];
  __shared__ __align__(16) unsigned short h2t[4][16][88];
  const int tid = threadIdx.x;
  const int lane = tid & 63, wv = tid >> 6;
  const int lrow = lane & 15, g16 = lane >> 4;

  // stage weights once
  {
    const uint4* s2 = (const uint4*)w2p;
    uint4* d2v = (uint4*)lw2;
    for (int i = tid; i < 512; i += 256) d2v[i] = s2[i];
    const uint4* s3 = (const uint4*)w3p;
    uint4* d3v = (uint4*)lw3;
    for (int i = tid; i < 1024; i += 256) d3v[i] = s3[i];
    if (tid < 192) w1r[tid / 64][tid % 64] = W1[(64 + tid / 64) * H1c + (tid % 64)];
  }
  const bf16x8* w2f = (const bf16x8*)lw2;
  const bf16x8* w3f = (const bf16x8*)lw3;

  const int g0 = blockIdx.x * 4;
  const int b = blockIdx.x >> 9;  // 512 blocks per cloud
  const float4* xp4 = (const float4*)(xpln + (size_t)b * NN);
  const float4* yp4 = (const float4*)(ypln + (size_t)b * NN);
  const float4* zp4 = (const float4*)(zpln + (size_t)b * NN);

  // ---- phase 1: per-wave ball query for centroid g0+wv ----
  {
    const int g = g0 + wv;
    const float cx = pos_out[g * 3 + 0], cy = pos_out[g * 3 + 1],
                cz = pos_out[g * 3 + 2];
    const ull lt = (1ull << lane) - 1ull;
    int cnt = 0;
    for (int t = 0; t < 16; ++t) {
      const int f4 = t * 64 + lane;
      float4 xv = xp4[f4], yv = yp4[f4], zv = zp4[f4];
      const int j0 = f4 * 4;
      {
        float d2 = d2_exact(xv.x, yv.x, zv.x, cx, cy, cz);
        bool pred = (d2 <= R2);
        ull mask = __ballot(pred);
        if (pred) {
          int p = cnt + (int)__popcll(mask & lt);
          if (p < CAP) kc[wv][p] = ((ull)__float_as_uint(d2) << 32) | (unsigned)(j0 + 0);
        }
        cnt += (int)__popcll(mask);
      }
      {
        float d2 = d2_exact(xv.y, yv.y, zv.y, cx, cy, cz);
        bool pred = (d2 <= R2);
        ull mask = __ballot(pred);
        if (pred) {
          int p = cnt + (int)__popcll(mask & lt);
          if (p < CAP) kc[wv][p] = ((ull)__float_as_uint(d2) << 32) | (unsigned)(j0 + 1);
        }
        cnt += (int)__popcll(mask);
      }
      {
        float d2 = d2_exact(xv.z, yv.z, zv.z, cx, cy, cz);
        bool pred = (d2 <= R2);
        ull mask = __ballot(pred);
        if (pred) {
          int p = cnt + (int)__popcll(mask & lt);
          if (p < CAP) kc[wv][p] = ((ull)__float_as_uint(d2) << 32) | (unsigned)(j0 + 2);
        }
        cnt += (int)__popcll(mask);
      }
      {
        float d2 = d2_exact(xv.w, yv.w, zv.w, cx, cy, cz);
        bool pred = (d2 <= R2);
        ull mask = __ballot(pred);
        if (pred) {
          int p = cnt + (int)__popcll(mask & lt);
          if (p < CAP) kc[wv][p] = ((ull)__float_as_uint(d2) << 32) | (unsigned)(j0 + 3);
        }
        cnt += (int)__popcll(mask);
      }
    }
    int M = cnt < CAP ? cnt : CAP;

    if (M <= 64) {
      nbl[wv][lane] =
          (lane < M) ? (b * NN + (int)(unsigned)(kc[wv][lane] & 0xffffffffu)) : -1;
    } else {
      ull mk[7];
      int rk[7];
#pragma unroll
      for (int q = 0; q < 7; q++) {
        int p = lane + q * 64;
        mk[q] = (p < M) ? kc[wv][p] : ~0ull;
        rk[q] = 0;
      }
      int i = 0;
      for (; i + 2 <= M; i += 2) {
        ull ka = kc[wv][i], kb2 = kc[wv][i + 1];
#pragma unroll
        for (int q = 0; q < 7; q++)
          rk[q] += (int)(ka < mk[q]) + (int)(kb2 < mk[q]);
      }
      if (i < M) {
        ull ka = kc[wv][i];
#pragma unroll
        for (int q = 0; q < 7; q++) rk[q] += (int)(ka < mk[q]);
      }
#pragma unroll
      for (int q = 0; q < 7; q++) {
        int p = lane + q * 64;
        if (p < M && rk[q] < KK)
          nbl[wv][rk[q]] = b * NN + (int)(unsigned)(mk[q] & 0xffffffffu);
      }
    }
  }
  __syncthreads();  // nbl visible to all waves

  // ---- phase 2: 4 MLP passes ----
  for (int pass = 0; pass < 4; ++pass) {
    const int g = g0 + pass;
    const float cx = pos_out[g * 3 + 0], cy = pos_out[g * 3 + 1],
                cz = pos_out[g * 3 + 2];
    const int* nl = nbl[pass];

    const int r = wv * 16 + lrow;
    const int j = nl[r];

    bf16x8 a0 = (bf16x8)0, a1 = (bf16x8)0;
    if (j >= 0) {
      const float rx = pos[j * 3 + 0] - cx;
      const float ry = pos[j * 3 + 1] - cy;
      const float rz = pos[j * 3 + 2] - cz;
      const unsigned short* yr = y1b + (size_t)j * H1c;
      uint4 vlo = *(const uint4*)(yr + 8 * g16);
      uint4 vhi = *(const uint4*)(yr + 32 + 8 * g16);
      const unsigned* plo = (const unsigned*)&vlo;
      const unsigned* phi = (const unsigned*)&vhi;
#pragma unroll
      for (int q = 0; q < 4; ++q) {
        unsigned u = plo[q];
        int k0 = 8 * g16 + 2 * q;
        float e0 = __uint_as_float(u << 16) + rx * w1r[0][k0] + ry * w1r[1][k0] +
                   rz * w1r[2][k0];
        float e1 = __uint_as_float(u & 0xffff0000u) + rx * w1r[0][k0 + 1] +
                   ry * w1r[1][k0 + 1] + rz * w1r[2][k0 + 1];
        a0[2 * q] = (short)f2bf(fmaxf(e0, 0.f));
        a0[2 * q + 1] = (short)f2bf(fmaxf(e1, 0.f));
        unsigned u2 = phi[q];
        int k1 = 32 + k0;
        float f0 = __uint_as_float(u2 << 16) + rx * w1r[0][k1] + ry * w1r[1][k1] +
                   rz * w1r[2][k1];
        float f1 = __uint_as_float(u2 & 0xffff0000u) + rx * w1r[0][k1 + 1] +
                   ry * w1r[1][k1 + 1] + rz * w1r[2][k1 + 1];
        a1[2 * q] = (short)f2bf(fmaxf(f0, 0.f));
        a1[2 * q + 1] = (short)f2bf(fmaxf(f1, 0.f));
      }
    }

#pragma unroll
    for (int c = 0; c < 4; ++c) {
      float bb = b2[c * 16 + lrow];
      f32x4 acc = {bb, bb, bb, bb};
      acc = __builtin_amdgcn_mfma_f32_16x16x32_bf16(a0, w2f[(c * 2 + 0) * 64 + lane], acc, 0, 0, 0);
      acc = __builtin_amdgcn_mfma_f32_16x16x32_bf16(a1, w2f[(c * 2 + 1) * 64 + lane], acc, 0, 0, 0);
#pragma unroll
      for (int t = 0; t < 4; ++t)
        h2t[wv][4 * g16 + t][c * 16 + lrow] = f2bf(fmaxf(acc[t], 0.f));
    }

    bf16x8 a20 = *(const bf16x8*)&h2t[wv][lrow][8 * g16];
    bf16x8 a21 = *(const bf16x8*)&h2t[wv][lrow][32 + 8 * g16];

    float vmax[8];
#pragma unroll
    for (int c = 0; c < 8; ++c) {
      float bb = b3[c * 16 + lrow];
      f32x4 acc = {bb, bb, bb, bb};
      acc = __builtin_amdgcn_mfma_f32_16x16x32_bf16(a20, w3f[(c * 2 + 0) * 64 + lane], acc, 0, 0, 0);
      acc = __builtin_amdgcn_mfma_f32_16x16x32_bf16(a21, w3f[(c * 2 + 1) * 64 + lane], acc, 0, 0, 0);
      float m = -INFINITY;
#pragma unroll
      for (int t = 0; t < 4; ++t) {
        int rg = wv * 16 + 4 * g16 + t;
        float val = (nl[rg] >= 0) ? fmaxf(acc[t], 0.f) : -INFINITY;
        m = fmaxf(m, val);
      }
      m = fmaxf(m, __shfl_xor(m, 16));
      m = fmaxf(m, __shfl_xor(m, 32));
      vmax[c] = m;
    }
    if (g16 == 0) {
#pragma unroll
      for (int c = 0; c < 8; ++c) red[wv][c * 16 + lrow] = vmax[c];
    }
    __syncthreads();
    if (tid < H3c) {
      float m = fmaxf(fmaxf(red[0][tid], red[1][tid]), fmaxf(red[2][tid], red[3][tid]));
      x_out[(size_t)g * H3c + tid] = m;
    }
    __syncthreads();  // retire red (and h2t) before next pass
  }
}

extern "C" void kernel_launch(void* const* d_in, const int* in_sizes, int n_in,
                              void* d_out, int out_size, void* d_ws, size_t ws_size,
                              hipStream_t stream) {
  const float* x = (const float*)d_in[0];
  const float* pos = (const float*)d_in[1];
  // d_in[2] = batch (int32) unused: clouds are equal-size by construction
  const float* W1 = (const float*)d_in[3];
  const float* b1 = (const float*)d_in[4];
  const float* W2 = (const float*)d_in[5];
  const float* b2 = (const float*)d_in[6];
  const float* W3 = (const float*)d_in[7];
  const float* b3 = (const float*)d_in[8];

  float* out = (float*)d_out;
  float* x_out = out;                                // [B*S, 128]
  float* pos_out = out + (size_t)BB * SS * H3c;      // [B*S, 3]
  float* batch_out = pos_out + (size_t)BB * SS * 3;  // [B*S]

  const size_t y1_bytes = (size_t)BB * NN * H1c * sizeof(unsigned short);  // 4 MB
  const size_t w2p_bytes = 4096 * sizeof(unsigned short);
  const size_t w3p_bytes = 8192 * sizeof(unsigned short);
  const size_t pln_bytes = (size_t)BB * NN * sizeof(float);                // 128 KB each
  if (ws_size < y1_bytes + w2p_bytes + w3p_bytes + 3 * pln_bytes) return;
  unsigned short* y1b = (unsigned short*)d_ws;
  unsigned short* w2p = (unsigned short*)((char*)d_ws + y1_bytes);
  unsigned short* w3p = w2p + 4096;
  float* xpln = (float*)((char*)d_ws + y1_bytes + w2p_bytes + w3p_bytes);
  float* ypln = xpln + BB * NN;
  float* zpln = ypln + BB * NN;

  fused_kernel<<<BB + 1 + NY1, 512, 0, stream>>>(pos, x, W1, b1, W2, W3, pos_out,
                                                 batch_out, y1b, w2p, w3p, xpln,
                                                 ypln, zpln);
  bqmlp_kernel<<<BB * SS / 4, 256, 0, stream>>>(pos, xpln, ypln, zpln, y1b, W1,
                                                b2, b3, w2p, w3p, pos_out, x_out);
}